// Round 1
// baseline (149.267 us; speedup 1.0000x reference)
//
#include <hip/hip_runtime.h>

// Per-batch confusion-matrix histogram:
//   gt  = trunc(segmap * 255.0f)            (f32 math, matches numpy/jax)
//   keep: gt != ignore (ignore = n_classes when use_dont_care else -1)
//   hist[b][pred][gt] += 1
//
// B=64, H=W=512, NC=19 -> out_size = 64*361 = 23104 int32.
// Memory-bound: 134 MB input reads; target ~21 us at 6.3 TB/s.

#define NC2_MAX 361  // 19*19 for this instance

__global__ __launch_bounds__(256) void zero_out_kernel(int* __restrict__ out, int n) {
    int i = blockIdx.x * 256 + threadIdx.x;
    if (i < n) out[i] = 0;
}

__global__ __launch_bounds__(256) void seg_hist_kernel(
    const int* __restrict__ pred,
    const float* __restrict__ seg,
    const int* __restrict__ ncls_p,
    const int* __restrict__ udc_p,
    int* __restrict__ out,
    int npix_per_batch,       // 262144
    int blocks_per_batch)     // gridDim.x
{
    __shared__ int hist[NC2_MAX];

    const int nc = ncls_p[0];
    const int nc2 = nc * nc;
    const int ignore = udc_p[0] ? nc : -1;

    const int b = blockIdx.y;
    const int tid = threadIdx.x;

    // zero LDS histogram
    for (int i = tid; i < NC2_MAX; i += 256) hist[i] = 0;
    __syncthreads();

    const size_t base = (size_t)b * (size_t)npix_per_batch;
    const int4*   p4 = (const int4*)(pred + base);
    const float4* s4 = (const float4*)(seg + base);
    const int nvec = npix_per_batch >> 2;  // pixels divisible by 4 here

    // grid-stride over this batch's vectorized pixels; consecutive lanes ->
    // consecutive 16B -> fully coalesced 1 KiB/wave loads
    for (int i = blockIdx.x * 256 + tid; i < nvec; i += blocks_per_batch * 256) {
        int4   p = p4[i];
        float4 s = s4[i];

        int g0 = (int)(s.x * 255.0f);
        int g1 = (int)(s.y * 255.0f);
        int g2 = (int)(s.z * 255.0f);
        int g3 = (int)(s.w * 255.0f);

        if (g0 != ignore) { int bin = p.x * nc + g0; if ((unsigned)bin < (unsigned)nc2) atomicAdd(&hist[bin], 1); }
        if (g1 != ignore) { int bin = p.y * nc + g1; if ((unsigned)bin < (unsigned)nc2) atomicAdd(&hist[bin], 1); }
        if (g2 != ignore) { int bin = p.z * nc + g2; if ((unsigned)bin < (unsigned)nc2) atomicAdd(&hist[bin], 1); }
        if (g3 != ignore) { int bin = p.w * nc + g3; if ((unsigned)bin < (unsigned)nc2) atomicAdd(&hist[bin], 1); }
    }
    __syncthreads();

    // flush block-private histogram to global (device-scope atomics)
    int* gout = out + (size_t)b * (size_t)nc2;
    for (int i = tid; i < nc2; i += 256) {
        int v = hist[i];
        if (v) atomicAdd(&gout[i], v);
    }
}

extern "C" void kernel_launch(void* const* d_in, const int* in_sizes, int n_in,
                              void* d_out, int out_size, void* d_ws, size_t ws_size,
                              hipStream_t stream) {
    const int*   pred = (const int*)d_in[0];
    const float* seg  = (const float*)d_in[1];
    const int*   ncp  = (const int*)d_in[2];
    const int*   udp  = (const int*)d_in[3];
    int* out = (int*)d_out;

    const int total_pix = in_sizes[0];         // B*H*W = 16777216
    // B from out_size assuming nc=19 (instance-fixed): out_size = B*361
    const int B = out_size / 361;              // 64
    const int npix_per_batch = total_pix / B;  // 262144

    // zero the output (harness poisons d_out with 0xAA before every launch)
    {
        int nblk = (out_size + 255) / 256;
        zero_out_kernel<<<nblk, 256, 0, stream>>>(out, out_size);
    }

    const int blocks_per_batch = 32;  // 32*64 = 2048 blocks = 8 per CU
    dim3 grid(blocks_per_batch, B);
    seg_hist_kernel<<<grid, 256, 0, stream>>>(pred, seg, ncp, udp, out,
                                              npix_per_batch, blocks_per_batch);
}